// Round 3
// baseline (3504.174 us; speedup 1.0000x reference)
//
#include <hip/hip_runtime.h>
#include <stddef.h>

// ---------- types / helpers ----------
using short8 = __attribute__((ext_vector_type(8))) short;
using f32x4  = __attribute__((ext_vector_type(4))) float;
using f32x16 = __attribute__((ext_vector_type(16))) float;
using u16x4  = __attribute__((ext_vector_type(4))) unsigned short;

__device__ __forceinline__ unsigned short cvt_bf16(float f) {
    unsigned u = __builtin_bit_cast(unsigned, f);
    u += 0x7fffu + ((u >> 16) & 1u);          // RNE
    return (unsigned short)(u >> 16);
}

__device__ __forceinline__ void gload_lds16(const void* g, void* l) {
    __builtin_amdgcn_global_load_lds(
        (const __attribute__((address_space(1))) unsigned*)g,
        (__attribute__((address_space(3))) unsigned*)l, 16, 0, 0);
}

#define MFMA16(a, b, c) __builtin_amdgcn_mfma_f32_16x16x32_bf16((a), (b), (c), 0, 0, 0)
#define MFMA32(a, b, c) __builtin_amdgcn_mfma_f32_32x32x16_bf16((a), (b), (c), 0, 0, 0)

struct SyncCell {               // 256B: counter and epoch on separate lines
    unsigned counter; unsigned pad0[31];
    unsigned epoch;   unsigned pad1[31];
};

// B=128, T=256, I=H=K=1024
// ---------- weight conversion: f32 -> bf16 ----------
__global__ __launch_bounds__(256) void convert_w(const float* __restrict__ Wi,
                                                 const float* __restrict__ Wh,
                                                 unsigned short* __restrict__ Wib,
                                                 unsigned short* __restrict__ Whb) {
    const float* src = blockIdx.y ? Wh : Wi;
    unsigned short* dst = blockIdx.y ? Whb : Wib;
    int base = blockIdx.x * 2048 + threadIdx.x * 8;
#pragma unroll
    for (int c = 0; c < 2; ++c) {
        float4 v = *(const float4*)(src + base + c * 4);
        u16x4 o;
        o.x = cvt_bf16(v.x); o.y = cvt_bf16(v.y); o.z = cvt_bf16(v.z); o.w = cvt_bf16(v.w);
        *(u16x4*)(dst + base + c * 4) = o;
    }
}

// ---------- h init + sync zero ----------
__global__ __launch_bounds__(256) void init_h(const float* __restrict__ hidden,
                                              unsigned short* __restrict__ h0,
                                              unsigned* __restrict__ syncw) {
    int row = blockIdx.x;
    int tid = threadIdx.x;
    float4 v = *(const float4*)(hidden + (size_t)row * 1024 + tid * 4);
    u16x4 o;
    o.x = cvt_bf16(v.x); o.y = cvt_bf16(v.y); o.z = cvt_bf16(v.z); o.w = cvt_bf16(v.w);
    *(u16x4*)(h0 + (size_t)row * 1024 + tid * 4) = o;
    if (blockIdx.x == 0) {
        for (int i = tid; i < 512; i += 256) syncw[i] = 0;   // 8 SyncCells
    }
}

// ---------- pre-GEMM: pre[t][b][n] = sum_k x[b][t][k] * Wi[n][k] + bi[n] ----------
__global__ __launch_bounds__(256) void pre_gemm(const float* __restrict__ x,
                                                const unsigned short* __restrict__ Wib,
                                                const float* __restrict__ bi,
                                                float* __restrict__ pre) {
    __shared__ unsigned short Alds[128 * 64];
    __shared__ unsigned short Blds[128 * 64];
    const int tid  = threadIdx.x;
    const int lane = tid & 63, wid = tid >> 6;
    const int wr = wid >> 1, wc = wid & 1;     // 2x2 waves, 64x64 each
    const int t  = blockIdx.y;                 // time index == M-tile
    const int n0 = blockIdx.x * 128;

    f32x4 acc[4][4] = {};

    for (int kt = 0; kt < 16; ++kt) {
        const int k0 = kt * 64;
        __syncthreads();
#pragma unroll
        for (int c = 0; c < 8; ++c) {
            int flat = c * 256 + tid;          // 0..2047
            int row = flat >> 4;               // 0..127  (batch b)
            int seg = flat & 15;               // 16 segs of 4 f32
            float4 v = *(const float4*)(x + (size_t)row * 262144 + (size_t)t * 1024 + k0 + seg * 4);
            u16x4 h;
            h.x = cvt_bf16(v.x); h.y = cvt_bf16(v.y); h.z = cvt_bf16(v.z); h.w = cvt_bf16(v.w);
            *(u16x4*)&Alds[row * 64 + seg * 4] = h;
        }
#pragma unroll
        for (int c = 0; c < 4; ++c) {
            int flat = c * 256 + tid;          // 0..1023
            int row = flat >> 3;               // 0..127
            int seg = flat & 7;                // 8 segs of 8 bf16
            gload_lds16(Wib + (size_t)(n0 + row) * 1024 + k0 + seg * 8, &Blds[flat * 8]);
        }
        __syncthreads();
#pragma unroll
        for (int ks = 0; ks < 2; ++ks) {
            short8 a[4], b[4];
#pragma unroll
            for (int i = 0; i < 4; ++i)
                a[i] = *(const short8*)&Alds[(wr * 64 + i * 16 + (lane & 15)) * 64 + ks * 32 + (lane >> 4) * 8];
#pragma unroll
            for (int j = 0; j < 4; ++j)
                b[j] = *(const short8*)&Blds[(wc * 64 + j * 16 + (lane & 15)) * 64 + ks * 32 + (lane >> 4) * 8];
#pragma unroll
            for (int i = 0; i < 4; ++i)
#pragma unroll
                for (int j = 0; j < 4; ++j)
                    acc[i][j] = MFMA16(a[i], b[j], acc[i][j]);
        }
    }
    const int rbase = wr * 64 + (lane >> 4) * 4;
    const int cbase = n0 + wc * 64 + (lane & 15);
#pragma unroll
    for (int i = 0; i < 4; ++i) {
#pragma unroll
        for (int j = 0; j < 4; ++j) {
            int n = cbase + j * 16;
            float bv = bi[n];
#pragma unroll
            for (int r = 0; r < 4; ++r) {
                int m = rbase + i * 16 + r;    // batch b
                pre[((size_t)t * 128 + m) * 1024 + n] = acc[i][j][r] + bv;
            }
        }
    }
}

// ---------- persistent scan kernel ----------
// 256 blocks x 256 threads. group g = bid&7 (g<4: fwd rows g*32.., g>=4: bwd),
// ni = bid>>3 -> n0 = ni*32. Per step: A (h rows) -> LDS swizzled; Wh frags in
// VGPRs; 4 waves K-split 32x32x16 MFMA; LDS reduce; softplus epilogue; group barrier.
__global__ __launch_bounds__(256, 1) void rnn_scan(const unsigned short* __restrict__ Whb,
                                                   const float* __restrict__ pre,
                                                   const float* __restrict__ bh,
                                                   unsigned short* __restrict__ ha,
                                                   unsigned short* __restrict__ hb,
                                                   float* __restrict__ out,
                                                   SyncCell* __restrict__ sync) {
    __shared__ unsigned short Alds[32 * 1024];   // 64KB, XOR-swizzled rows
    __shared__ float Red[4][1024];               // 16KB cross-wave reduce

    const int tid  = threadIdx.x;
    const int lane = tid & 63, wid = tid >> 6;
    const int bid  = blockIdx.x;
    const int g    = bid & 7, ni = bid >> 3;
    const int m0   = g * 32, n0 = ni * 32;
    const bool fwd = (g < 4);

    // Wh fragments resident in VGPRs: wave wid owns k in [wid*256, wid*256+256)
    short8 bfrag[16];
    {
        const unsigned short* bp = Whb + (size_t)(n0 + (lane & 31)) * 1024
                                 + wid * 256 + (lane >> 5) * 8;
#pragma unroll
        for (int ks = 0; ks < 16; ++ks)
            bfrag[ks] = *(const short8*)(bp + ks * 16);
    }

    // epilogue constants: thread owns 4 consecutive n at one row
    const int mloc = tid >> 3;            // 0..31
    const int nloc = (tid & 7) * 4;       // 0..28
    const int m    = m0 + mloc;
    const int b    = m & 127;
    const int n    = n0 + nloc;
    const float4 bh4 = *(const float4*)(bh + n);
    float* outp      = out + (size_t)b * 524288 + (fwd ? 0 : 1024) + n;
    const float* prebase = pre + (size_t)b * 1024 + n;
    unsigned* ep  = &sync[g].epoch;
    unsigned* cnt = &sync[g].counter;

    const char* aswz_base = (const char*)Alds + (lane & 31) * 2048;
    const int   aswz      = (lane & 7) << 4;             // (row&7)<<4, row=lane&31
    const int   kb0       = wid * 512 + (lane >> 5) * 16;

    for (int s = 0; s < 256; ++s) {
        const unsigned short* hin = (s & 1) ? hb : ha;
        unsigned short* hout      = (s & 1) ? ha : hb;
        const int prow = fwd ? s : 255 - s;
        // prefetch pre tile before the barrier spin (independent of h)
        float4 pv = *(const float4*)(prebase + (size_t)prow * 131072);

        if (s > 0 && tid == 0) {
            int fuel = 1 << 22;
            while (__hip_atomic_load(ep, __ATOMIC_RELAXED, __HIP_MEMORY_SCOPE_AGENT) < (unsigned)s
                   && --fuel)
                __builtin_amdgcn_s_sleep(1);
            (void)__hip_atomic_load(ep, __ATOMIC_ACQUIRE, __HIP_MEMORY_SCOPE_AGENT);
        }
        __syncthreads();

        // stage A: h rows m0..m0+31, all K, swizzled source -> linear LDS dest
        {
            const char* hbase = (const char*)(hin + (size_t)m0 * 1024);
#pragma unroll
            for (int c = 0; c < 16; ++c) {
                int flat = c * 256 + tid;                 // 0..4095 chunks of 16B
                int row  = flat >> 7;                     // 0..31
                int cb   = (flat & 127) * 16;             // byte col in row
                gload_lds16(hbase + row * 2048 + (cb ^ ((row & 7) << 4)), &Alds[flat * 8]);
            }
        }
        asm volatile("s_waitcnt vmcnt(0)" ::: "memory");
        __syncthreads();

        // K-split MFMA: each wave 32x32 partial over its K=256 slice
        f32x16 acc0 = {}, acc1 = {};
#pragma unroll
        for (int ks = 0; ks < 16; ++ks) {
            short8 a = *(const short8*)(aswz_base + ((kb0 + ks * 32) ^ aswz));
            if (ks & 1) acc1 = MFMA32(a, bfrag[ks], acc1);
            else        acc0 = MFMA32(a, bfrag[ks], acc0);
        }
        f32x16 acc = acc0 + acc1;
#pragma unroll
        for (int r = 0; r < 16; ++r) {
            int row = (r & 3) + 8 * (r >> 2) + 4 * (lane >> 5);
            Red[wid][row * 32 + (lane & 31)] = acc[r];
        }
        __syncthreads();

        // reduce 4 waves + epilogue
        {
            const int o = tid * 4;
            float4 q0 = *(const float4*)&Red[0][o];
            float4 q1 = *(const float4*)&Red[1][o];
            float4 q2 = *(const float4*)&Red[2][o];
            float4 q3 = *(const float4*)&Red[3][o];
            float vv[4] = { q0.x + q1.x + q2.x + q3.x + pv.x + bh4.x,
                            q0.y + q1.y + q2.y + q3.y + pv.y + bh4.y,
                            q0.z + q1.z + q2.z + q3.z + pv.z + bh4.z,
                            q0.w + q1.w + q2.w + q3.w + pv.w + bh4.w };
            f32x4 ov;
            u16x4 hh;
#pragma unroll
            for (int j = 0; j < 4; ++j) {
                float xv = vv[j];
                float hv = (5.0f * xv > 20.0f) ? xv : 0.2f * log1pf(__expf(5.0f * xv));
                ov[j] = hv;
                hh[j] = cvt_bf16(hv);
            }
            *(u16x4*)(hout + (size_t)m * 1024 + n) = hh;
            int tout = fwd ? ((239 - s) & 255) : s;
            __builtin_nontemporal_store(ov, (f32x4*)(outp + (size_t)tout * 2048));
        }
        __syncthreads();   // drains vmcnt per wave -> stores are in L2

        if (s < 255 && tid == 0) {
            unsigned c = __hip_atomic_fetch_add(cnt, 1u, __ATOMIC_ACQ_REL,
                                                __HIP_MEMORY_SCOPE_AGENT);
            if (c == (unsigned)(32 * (s + 1) - 1))
                __hip_atomic_store(ep, (unsigned)(s + 1), __ATOMIC_RELEASE,
                                   __HIP_MEMORY_SCOPE_AGENT);
        }
    }
}

// ---------- launch ----------
extern "C" void kernel_launch(void* const* d_in, const int* in_sizes, int n_in,
                              void* d_out, int out_size, void* d_ws, size_t ws_size,
                              hipStream_t stream) {
    const float* x      = (const float*)d_in[0];
    const float* hidden = (const float*)d_in[1];
    const float* Wi     = (const float*)d_in[2];
    const float* bi     = (const float*)d_in[3];
    const float* Wh     = (const float*)d_in[4];
    const float* bh     = (const float*)d_in[5];
    float* out = (float*)d_out;

    char* ws = (char*)d_ws;
    float*          pre = (float*)ws;                               // 128 MB
    unsigned short* Wib = (unsigned short*)(ws + 134217728);        // 2 MB
    unsigned short* Whb = (unsigned short*)(ws + 136314880);        // 2 MB
    unsigned short* ha  = (unsigned short*)(ws + 138412032);        // 512 KB
    unsigned short* hb  = (unsigned short*)(ws + 138936320);        // 512 KB
    SyncCell*      sync = (SyncCell*)(ws + 139460608);              // 2 KB

    convert_w<<<dim3(512, 2), 256, 0, stream>>>(Wi, Wh, Wib, Whb);
    init_h<<<256, 256, 0, stream>>>(hidden, ha, (unsigned*)sync);
    pre_gemm<<<dim3(8, 256), 256, 0, stream>>>(x, Wib, bi, pre);
    rnn_scan<<<256, 256, 0, stream>>>(Whb, pre, bh, ha, hb, out, sync);
}

// Round 4
// 1444.250 us; speedup vs baseline: 2.4263x; 2.4263x over previous
//
#include <hip/hip_runtime.h>
#include <stddef.h>

// ---------- types / helpers ----------
using short8 = __attribute__((ext_vector_type(8))) short;
using f32x4  = __attribute__((ext_vector_type(4))) float;
using f32x16 = __attribute__((ext_vector_type(16))) float;
using u16x4  = __attribute__((ext_vector_type(4))) unsigned short;

__device__ __forceinline__ unsigned short cvt_bf16(float f) {
    unsigned u = __builtin_bit_cast(unsigned, f);
    u += 0x7fffu + ((u >> 16) & 1u);          // RNE
    return (unsigned short)(u >> 16);
}

__device__ __forceinline__ void gload_lds16(const void* g, void* l) {
    __builtin_amdgcn_global_load_lds(
        (const __attribute__((address_space(1))) unsigned*)g,
        (__attribute__((address_space(3))) unsigned*)l, 16, 0, 0);
}

#define MFMA16(a, b, c) __builtin_amdgcn_mfma_f32_16x16x32_bf16((a), (b), (c), 0, 0, 0)
#define MFMA32(a, b, c) __builtin_amdgcn_mfma_f32_32x32x16_bf16((a), (b), (c), 0, 0, 0)

struct SyncCell {               // 256B: counter and epoch on separate lines
    unsigned counter; unsigned pad0[31];
    unsigned epoch;   unsigned pad1[31];
};

// B=128, T=256, I=H=K=1024
// ---------- weight conversion: f32 -> bf16 ----------
__global__ __launch_bounds__(256) void convert_w(const float* __restrict__ Wi,
                                                 const float* __restrict__ Wh,
                                                 unsigned short* __restrict__ Wib,
                                                 unsigned short* __restrict__ Whb) {
    const float* src = blockIdx.y ? Wh : Wi;
    unsigned short* dst = blockIdx.y ? Whb : Wib;
    int base = blockIdx.x * 2048 + threadIdx.x * 8;
#pragma unroll
    for (int c = 0; c < 2; ++c) {
        float4 v = *(const float4*)(src + base + c * 4);
        u16x4 o;
        o.x = cvt_bf16(v.x); o.y = cvt_bf16(v.y); o.z = cvt_bf16(v.z); o.w = cvt_bf16(v.w);
        *(u16x4*)(dst + base + c * 4) = o;
    }
}

// ---------- h init + sync zero ----------
__global__ __launch_bounds__(256) void init_h(const float* __restrict__ hidden,
                                              unsigned short* __restrict__ h0,
                                              unsigned* __restrict__ syncw) {
    int row = blockIdx.x;
    int tid = threadIdx.x;
    float4 v = *(const float4*)(hidden + (size_t)row * 1024 + tid * 4);
    u16x4 o;
    o.x = cvt_bf16(v.x); o.y = cvt_bf16(v.y); o.z = cvt_bf16(v.z); o.w = cvt_bf16(v.w);
    *(u16x4*)(h0 + (size_t)row * 1024 + tid * 4) = o;
    if (blockIdx.x == 0) {
        for (int i = tid; i < 512; i += 256) syncw[i] = 0;   // 8 SyncCells
    }
}

// ---------- pre-GEMM: pre[t][b][n] = sum_k x[b][t][k] * Wi[n][k] + bi[n] ----------
__global__ __launch_bounds__(256) void pre_gemm(const float* __restrict__ x,
                                                const unsigned short* __restrict__ Wib,
                                                const float* __restrict__ bi,
                                                float* __restrict__ pre) {
    __shared__ unsigned short Alds[128 * 64];
    __shared__ unsigned short Blds[128 * 64];
    const int tid  = threadIdx.x;
    const int lane = tid & 63, wid = tid >> 6;
    const int wr = wid >> 1, wc = wid & 1;     // 2x2 waves, 64x64 each
    const int t  = blockIdx.y;                 // time index == M-tile
    const int n0 = blockIdx.x * 128;

    f32x4 acc[4][4] = {};

    for (int kt = 0; kt < 16; ++kt) {
        const int k0 = kt * 64;
        __syncthreads();
#pragma unroll
        for (int c = 0; c < 8; ++c) {
            int flat = c * 256 + tid;          // 0..2047
            int row = flat >> 4;               // 0..127  (batch b)
            int seg = flat & 15;               // 16 segs of 4 f32
            float4 v = *(const float4*)(x + (size_t)row * 262144 + (size_t)t * 1024 + k0 + seg * 4);
            u16x4 h;
            h.x = cvt_bf16(v.x); h.y = cvt_bf16(v.y); h.z = cvt_bf16(v.z); h.w = cvt_bf16(v.w);
            *(u16x4*)&Alds[row * 64 + seg * 4] = h;
        }
#pragma unroll
        for (int c = 0; c < 4; ++c) {
            int flat = c * 256 + tid;          // 0..1023
            int row = flat >> 3;               // 0..127
            int seg = flat & 7;                // 8 segs of 8 bf16
            gload_lds16(Wib + (size_t)(n0 + row) * 1024 + k0 + seg * 8, &Blds[flat * 8]);
        }
        __syncthreads();
#pragma unroll
        for (int ks = 0; ks < 2; ++ks) {
            short8 a[4], b[4];
#pragma unroll
            for (int i = 0; i < 4; ++i)
                a[i] = *(const short8*)&Alds[(wr * 64 + i * 16 + (lane & 15)) * 64 + ks * 32 + (lane >> 4) * 8];
#pragma unroll
            for (int j = 0; j < 4; ++j)
                b[j] = *(const short8*)&Blds[(wc * 64 + j * 16 + (lane & 15)) * 64 + ks * 32 + (lane >> 4) * 8];
#pragma unroll
            for (int i = 0; i < 4; ++i)
#pragma unroll
                for (int j = 0; j < 4; ++j)
                    acc[i][j] = MFMA16(a[i], b[j], acc[i][j]);
        }
    }
    const int rbase = wr * 64 + (lane >> 4) * 4;
    const int cbase = n0 + wc * 64 + (lane & 15);
#pragma unroll
    for (int i = 0; i < 4; ++i) {
#pragma unroll
        for (int j = 0; j < 4; ++j) {
            int n = cbase + j * 16;
            float bv = bi[n];
#pragma unroll
            for (int r = 0; r < 4; ++r) {
                int m = rbase + i * 16 + r;    // batch b
                pre[((size_t)t * 128 + m) * 1024 + n] = acc[i][j][r] + bv;
            }
        }
    }
}

// ---------- persistent scan kernel ----------
// 256 blocks x 256 threads. group g = bid&7 (g<4: fwd rows g*32.., g>=4: bwd),
// ni = bid>>3 -> n0 = ni*32. All h traffic + sync flags are RELAXED agent-scope
// atomics (sc1, coherent at IFC) -> no buffer_wbl2/buffer_inv ever emitted.
__global__ __launch_bounds__(256, 1) void rnn_scan(const unsigned short* __restrict__ Whb,
                                                   const float* __restrict__ pre,
                                                   const float* __restrict__ bh,
                                                   unsigned short* __restrict__ ha,
                                                   unsigned short* __restrict__ hb,
                                                   float* __restrict__ out,
                                                   SyncCell* __restrict__ sync) {
    __shared__ unsigned short Alds[32 * 1024];   // 64KB, XOR-swizzled rows
    __shared__ float Red[4][1024];               // 16KB cross-wave reduce

    const int tid  = threadIdx.x;
    const int lane = tid & 63, wid = tid >> 6;
    const int bid  = blockIdx.x;
    const int g    = bid & 7, ni = bid >> 3;
    const int m0   = g * 32, n0 = ni * 32;
    const bool fwd = (g < 4);

    // Wh fragments resident in VGPRs: wave wid owns k in [wid*256, wid*256+256)
    short8 bfrag[16];
    {
        const unsigned short* bp = Whb + (size_t)(n0 + (lane & 31)) * 1024
                                 + wid * 256 + (lane >> 5) * 8;
#pragma unroll
        for (int ks = 0; ks < 16; ++ks)
            bfrag[ks] = *(const short8*)(bp + ks * 16);
    }

    // epilogue constants: thread owns 4 consecutive n at one row
    const int mloc = tid >> 3;            // 0..31
    const int nloc = (tid & 7) * 4;       // 0..28
    const int m    = m0 + mloc;
    const int b    = m & 127;
    const int n    = n0 + nloc;
    const float4 bh4 = *(const float4*)(bh + n);
    float* outp      = out + (size_t)b * 524288 + (fwd ? 0 : 1024) + n;
    const float* prebase = pre + (size_t)b * 1024 + n;
    unsigned* ep  = &sync[g].epoch;
    unsigned* cnt = &sync[g].counter;

    const char* aswz_base = (const char*)Alds + (lane & 31) * 2048;
    const int   aswz      = (lane & 7) << 4;             // (row&7)<<4, row=lane&31
    const int   kb0       = wid * 512 + (lane >> 5) * 16;

    for (int s = 0; s < 256; ++s) {
        const unsigned short* hin = (s & 1) ? hb : ha;
        unsigned short* hout      = (s & 1) ? ha : hb;
        const int prow = fwd ? s : 255 - s;
        // prefetch pre tile before the barrier spin (independent of h)
        float4 pv = *(const float4*)(prebase + (size_t)prow * 131072);

        if (s > 0 && tid == 0) {
            int fuel = 1 << 22;
            while (__hip_atomic_load(ep, __ATOMIC_RELAXED, __HIP_MEMORY_SCOPE_AGENT) < (unsigned)s
                   && --fuel)
                __builtin_amdgcn_s_sleep(1);
        }
        __syncthreads();

        // stage A: h rows m0..m0+31 (32 x 2048B) via relaxed sc1 8B loads ->
        // XOR-swizzled ds_write. Thread tid covers column bytes [tid*8, tid*8+8)
        // of every row. Two phases of 16 to bound VGPRs while batching loads.
        {
            const unsigned long long* hsrc =
                (const unsigned long long*)(hin + (size_t)m0 * 1024);
            const int colswz = tid * 8;
#pragma unroll
            for (int ph = 0; ph < 2; ++ph) {
                unsigned long long tmp[16];
#pragma unroll
                for (int i = 0; i < 16; ++i)
                    tmp[i] = __hip_atomic_load(&hsrc[(size_t)(ph * 16 + i) * 256 + tid],
                                               __ATOMIC_RELAXED, __HIP_MEMORY_SCOPE_AGENT);
#pragma unroll
                for (int i = 0; i < 16; ++i) {
                    int row = ph * 16 + i;
                    *(unsigned long long*)((char*)Alds + row * 2048
                                           + (colswz ^ ((row & 7) << 4))) = tmp[i];
                }
            }
        }
        __syncthreads();

        // K-split MFMA: each wave 32x32 partial over its K=256 slice
        f32x16 acc0 = {}, acc1 = {};
#pragma unroll
        for (int ks = 0; ks < 16; ++ks) {
            short8 a = *(const short8*)(aswz_base + ((kb0 + ks * 32) ^ aswz));
            if (ks & 1) acc1 = MFMA32(a, bfrag[ks], acc1);
            else        acc0 = MFMA32(a, bfrag[ks], acc0);
        }
        f32x16 acc = acc0 + acc1;
#pragma unroll
        for (int r = 0; r < 16; ++r) {
            int row = (r & 3) + 8 * (r >> 2) + 4 * (lane >> 5);
            Red[wid][row * 32 + (lane & 31)] = acc[r];
        }
        __syncthreads();

        // reduce 4 waves + epilogue
        {
            const int o = tid * 4;
            float4 q0 = *(const float4*)&Red[0][o];
            float4 q1 = *(const float4*)&Red[1][o];
            float4 q2 = *(const float4*)&Red[2][o];
            float4 q3 = *(const float4*)&Red[3][o];
            float vv[4] = { q0.x + q1.x + q2.x + q3.x + pv.x + bh4.x,
                            q0.y + q1.y + q2.y + q3.y + pv.y + bh4.y,
                            q0.z + q1.z + q2.z + q3.z + pv.z + bh4.z,
                            q0.w + q1.w + q2.w + q3.w + pv.w + bh4.w };
            f32x4 ov;
            u16x4 hh;
#pragma unroll
            for (int j = 0; j < 4; ++j) {
                float xv = vv[j];
                float hv = (5.0f * xv > 20.0f) ? xv : 0.2f * log1pf(__expf(5.0f * xv));
                ov[j] = hv;
                hh[j] = cvt_bf16(hv);
            }
            __hip_atomic_store((unsigned long long*)(hout + (size_t)m * 1024 + n),
                               __builtin_bit_cast(unsigned long long, hh),
                               __ATOMIC_RELAXED, __HIP_MEMORY_SCOPE_AGENT);
            int tout = fwd ? ((239 - s) & 255) : s;
            __builtin_nontemporal_store(ov, (f32x4*)(outp + (size_t)tout * 2048));
        }
        asm volatile("s_waitcnt vmcnt(0)" ::: "memory");   // h stores acked at IFC
        __syncthreads();

        if (s < 255 && tid == 0) {
            unsigned c = __hip_atomic_fetch_add(cnt, 1u, __ATOMIC_RELAXED,
                                                __HIP_MEMORY_SCOPE_AGENT);
            if (c == (unsigned)(32 * (s + 1) - 1))
                __hip_atomic_store(ep, (unsigned)(s + 1), __ATOMIC_RELAXED,
                                   __HIP_MEMORY_SCOPE_AGENT);
        }
    }
}

// ---------- launch ----------
extern "C" void kernel_launch(void* const* d_in, const int* in_sizes, int n_in,
                              void* d_out, int out_size, void* d_ws, size_t ws_size,
                              hipStream_t stream) {
    const float* x      = (const float*)d_in[0];
    const float* hidden = (const float*)d_in[1];
    const float* Wi     = (const float*)d_in[2];
    const float* bi     = (const float*)d_in[3];
    const float* Wh     = (const float*)d_in[4];
    const float* bh     = (const float*)d_in[5];
    float* out = (float*)d_out;

    char* ws = (char*)d_ws;
    float*          pre = (float*)ws;                               // 128 MB
    unsigned short* Wib = (unsigned short*)(ws + 134217728);        // 2 MB
    unsigned short* Whb = (unsigned short*)(ws + 136314880);        // 2 MB
    unsigned short* ha  = (unsigned short*)(ws + 138412032);        // 512 KB
    unsigned short* hb  = (unsigned short*)(ws + 138936320);        // 512 KB
    SyncCell*      sync = (SyncCell*)(ws + 139460608);              // 2 KB

    convert_w<<<dim3(512, 2), 256, 0, stream>>>(Wi, Wh, Wib, Whb);
    init_h<<<256, 256, 0, stream>>>(hidden, ha, (unsigned*)sync);
    pre_gemm<<<dim3(8, 256), 256, 0, stream>>>(x, Wib, bi, pre);
    rnn_scan<<<256, 256, 0, stream>>>(Whb, pre, bh, ha, hb, out, sync);
}

// Round 5
// 1214.189 us; speedup vs baseline: 2.8860x; 1.1895x over previous
//
#include <hip/hip_runtime.h>
#include <stddef.h>

// ---------- types / helpers ----------
using short8 = __attribute__((ext_vector_type(8))) short;
using f32x4  = __attribute__((ext_vector_type(4))) float;
using f32x16 = __attribute__((ext_vector_type(16))) float;
using u16x4  = __attribute__((ext_vector_type(4))) unsigned short;

__device__ __forceinline__ unsigned short cvt_bf16(float f) {
    unsigned u = __builtin_bit_cast(unsigned, f);
    u += 0x7fffu + ((u >> 16) & 1u);          // RNE
    return (unsigned short)(u >> 16);
}

__device__ __forceinline__ void gload_lds16(const void* g, void* l) {
    __builtin_amdgcn_global_load_lds(
        (const __attribute__((address_space(1))) unsigned*)g,
        (__attribute__((address_space(3))) unsigned*)l, 16, 0, 0);
}

#define MFMA16(a, b, c) __builtin_amdgcn_mfma_f32_16x16x32_bf16((a), (b), (c), 0, 0, 0)
#define MFMA32(a, b, c) __builtin_amdgcn_mfma_f32_32x32x16_bf16((a), (b), (c), 0, 0, 0)

// B=128, T=256, I=H=K=1024
// ---------- weight conversion: f32 -> bf16 ----------
__global__ __launch_bounds__(256) void convert_w(const float* __restrict__ Wi,
                                                 const float* __restrict__ Wh,
                                                 unsigned short* __restrict__ Wib,
                                                 unsigned short* __restrict__ Whb) {
    const float* src = blockIdx.y ? Wh : Wi;
    unsigned short* dst = blockIdx.y ? Whb : Wib;
    int base = blockIdx.x * 2048 + threadIdx.x * 8;
#pragma unroll
    for (int c = 0; c < 2; ++c) {
        float4 v = *(const float4*)(src + base + c * 4);
        u16x4 o;
        o.x = cvt_bf16(v.x); o.y = cvt_bf16(v.y); o.z = cvt_bf16(v.z); o.w = cvt_bf16(v.w);
        *(u16x4*)(dst + base + c * 4) = o;
    }
}

// ---------- h init + flag zero ----------
__global__ __launch_bounds__(256) void init_h(const float* __restrict__ hidden,
                                              unsigned short* __restrict__ h0,
                                              unsigned* __restrict__ flags) {
    int row = blockIdx.x;
    int tid = threadIdx.x;
    float4 v = *(const float4*)(hidden + (size_t)row * 1024 + tid * 4);
    u16x4 o;
    o.x = cvt_bf16(v.x); o.y = cvt_bf16(v.y); o.z = cvt_bf16(v.z); o.w = cvt_bf16(v.w);
    *(u16x4*)(h0 + (size_t)row * 1024 + tid * 4) = o;
    if (blockIdx.x == 0 && tid < 256) flags[tid] = 0;   // 8 groups x 32 slots
}

// ---------- pre-GEMM: pre[t][b][n] = sum_k x[b][t][k] * Wi[n][k] + bi[n] ----------
__global__ __launch_bounds__(256) void pre_gemm(const float* __restrict__ x,
                                                const unsigned short* __restrict__ Wib,
                                                const float* __restrict__ bi,
                                                float* __restrict__ pre) {
    __shared__ unsigned short Alds[128 * 64];
    __shared__ unsigned short Blds[128 * 64];
    const int tid  = threadIdx.x;
    const int lane = tid & 63, wid = tid >> 6;
    const int wr = wid >> 1, wc = wid & 1;     // 2x2 waves, 64x64 each
    const int t  = blockIdx.y;                 // time index == M-tile
    const int n0 = blockIdx.x * 128;

    f32x4 acc[4][4] = {};

    for (int kt = 0; kt < 16; ++kt) {
        const int k0 = kt * 64;
        __syncthreads();
#pragma unroll
        for (int c = 0; c < 8; ++c) {
            int flat = c * 256 + tid;          // 0..2047
            int row = flat >> 4;               // 0..127  (batch b)
            int seg = flat & 15;               // 16 segs of 4 f32
            float4 v = *(const float4*)(x + (size_t)row * 262144 + (size_t)t * 1024 + k0 + seg * 4);
            u16x4 h;
            h.x = cvt_bf16(v.x); h.y = cvt_bf16(v.y); h.z = cvt_bf16(v.z); h.w = cvt_bf16(v.w);
            *(u16x4*)&Alds[row * 64 + seg * 4] = h;
        }
#pragma unroll
        for (int c = 0; c < 4; ++c) {
            int flat = c * 256 + tid;          // 0..1023
            int row = flat >> 3;               // 0..127
            int seg = flat & 7;                // 8 segs of 8 bf16
            gload_lds16(Wib + (size_t)(n0 + row) * 1024 + k0 + seg * 8, &Blds[flat * 8]);
        }
        __syncthreads();
#pragma unroll
        for (int ks = 0; ks < 2; ++ks) {
            short8 a[4], b[4];
#pragma unroll
            for (int i = 0; i < 4; ++i)
                a[i] = *(const short8*)&Alds[(wr * 64 + i * 16 + (lane & 15)) * 64 + ks * 32 + (lane >> 4) * 8];
#pragma unroll
            for (int j = 0; j < 4; ++j)
                b[j] = *(const short8*)&Blds[(wc * 64 + j * 16 + (lane & 15)) * 64 + ks * 32 + (lane >> 4) * 8];
#pragma unroll
            for (int i = 0; i < 4; ++i)
#pragma unroll
                for (int j = 0; j < 4; ++j)
                    acc[i][j] = MFMA16(a[i], b[j], acc[i][j]);
        }
    }
    const int rbase = wr * 64 + (lane >> 4) * 4;
    const int cbase = n0 + wc * 64 + (lane & 15);
#pragma unroll
    for (int i = 0; i < 4; ++i) {
#pragma unroll
        for (int j = 0; j < 4; ++j) {
            int n = cbase + j * 16;
            float bv = bi[n];
#pragma unroll
            for (int r = 0; r < 4; ++r) {
                int m = rbase + i * 16 + r;    // batch b
                pre[((size_t)t * 128 + m) * 1024 + n] = acc[i][j][r] + bv;
            }
        }
    }
}

// ---------- persistent scan kernel ----------
// 256 blocks x 256 threads. group g = bid&7 (g<4: fwd rows g*32.., g>=4: bwd),
// ni = bid>>3 -> n0 = ni*32. h traffic relaxed agent-scope (IFC-coherent, no
// cache maintenance). Barrier = per-block flag store + 32-lane vector poll.
__global__ __launch_bounds__(256, 1) void rnn_scan(const unsigned short* __restrict__ Whb,
                                                   const float* __restrict__ pre,
                                                   const float* __restrict__ bh,
                                                   unsigned short* __restrict__ ha,
                                                   unsigned short* __restrict__ hb,
                                                   float* __restrict__ out,
                                                   unsigned* __restrict__ flags) {
    __shared__ unsigned short Alds[32 * 1024];   // 64KB, XOR-swizzled rows
    __shared__ float Red[4][1024];               // 16KB cross-wave reduce

    const int tid  = threadIdx.x;
    const int lane = tid & 63, wid = tid >> 6;
    const int bid  = blockIdx.x;
    const int g    = bid & 7, ni = bid >> 3;
    const int m0   = g * 32, n0 = ni * 32;
    const bool fwd = (g < 4);
    unsigned* gflags = flags + g * 32;

    // Wh fragments resident in VGPRs: wave wid owns k in [wid*256, wid*256+256)
    short8 bfrag[16];
    {
        const unsigned short* bp = Whb + (size_t)(n0 + (lane & 31)) * 1024
                                 + wid * 256 + (lane >> 5) * 8;
#pragma unroll
        for (int ks = 0; ks < 16; ++ks)
            bfrag[ks] = *(const short8*)(bp + ks * 16);
    }

    // epilogue constants: thread owns 4 consecutive n at one row
    const int mloc = tid >> 3;            // 0..31
    const int nloc = (tid & 7) * 4;       // 0..28
    const int m    = m0 + mloc;
    const int b    = m & 127;
    const int n    = n0 + nloc;
    const float4 bh4 = *(const float4*)(bh + n);
    float* outp      = out + (size_t)b * 524288 + (fwd ? 0 : 1024) + n;
    const float* prebase = pre + (size_t)b * 1024 + n;

    const char* aswz_base = (const char*)Alds + (lane & 31) * 2048;
    const int   aswz      = (lane & 7) << 4;             // (row&7)<<4, row=lane&31
    const int   kb0       = wid * 512 + (lane >> 5) * 16;

    for (int s = 0; s < 256; ++s) {
        const unsigned short* hin = (s & 1) ? hb : ha;
        unsigned short* hout      = (s & 1) ? ha : hb;
        const int prow = fwd ? s : 255 - s;
        // prefetch pre tile before the poll (independent of h)
        float4 pv = *(const float4*)(prebase + (size_t)prow * 131072);

        if (s > 0) {
            if (tid < 64) {
                int fuel = 1 << 20;
                unsigned v;
                do {
                    v = __hip_atomic_load(&gflags[lane & 31], __ATOMIC_RELAXED,
                                          __HIP_MEMORY_SCOPE_AGENT);
                } while (!__all((int)(v >= (unsigned)s)) && --fuel);
            }
            __syncthreads();
        }

        // stage A: h rows m0..m0+31 (32 x 2048B) via relaxed 8B loads ->
        // XOR-swizzled ds_write. Thread tid covers bytes [tid*8, tid*8+8) of
        // every row. Single batch of 32 -> one latency exposure.
        {
            const unsigned long long* hsrc =
                (const unsigned long long*)(hin + (size_t)m0 * 1024);
            const int colswz = tid * 8;
            unsigned long long tmp[32];
#pragma unroll
            for (int i = 0; i < 32; ++i)
                tmp[i] = __hip_atomic_load(&hsrc[(size_t)i * 256 + tid],
                                           __ATOMIC_RELAXED, __HIP_MEMORY_SCOPE_AGENT);
#pragma unroll
            for (int i = 0; i < 32; ++i)
                *(unsigned long long*)((char*)Alds + i * 2048
                                       + (colswz ^ ((i & 7) << 4))) = tmp[i];
        }
        __syncthreads();

        // K-split MFMA: each wave 32x32 partial over its K=256 slice
        f32x16 acc0 = {}, acc1 = {};
#pragma unroll
        for (int ks = 0; ks < 16; ++ks) {
            short8 a = *(const short8*)(aswz_base + ((kb0 + ks * 32) ^ aswz));
            if (ks & 1) acc1 = MFMA32(a, bfrag[ks], acc1);
            else        acc0 = MFMA32(a, bfrag[ks], acc0);
        }
        f32x16 acc = acc0 + acc1;
#pragma unroll
        for (int r = 0; r < 16; ++r) {
            int row = (r & 3) + 8 * (r >> 2) + 4 * (lane >> 5);
            Red[wid][row * 32 + (lane & 31)] = acc[r];
        }
        __syncthreads();

        // reduce 4 waves + epilogue
        f32x4 ov;
        {
            const int o = tid * 4;
            float4 q0 = *(const float4*)&Red[0][o];
            float4 q1 = *(const float4*)&Red[1][o];
            float4 q2 = *(const float4*)&Red[2][o];
            float4 q3 = *(const float4*)&Red[3][o];
            float vv[4] = { q0.x + q1.x + q2.x + q3.x + pv.x + bh4.x,
                            q0.y + q1.y + q2.y + q3.y + pv.y + bh4.y,
                            q0.z + q1.z + q2.z + q3.z + pv.z + bh4.z,
                            q0.w + q1.w + q2.w + q3.w + pv.w + bh4.w };
            u16x4 hh;
#pragma unroll
            for (int j = 0; j < 4; ++j) {
                float xv = vv[j];
                float hv = (5.0f * xv > 20.0f) ? xv : 0.2f * log1pf(__expf(5.0f * xv));
                ov[j] = hv;
                hh[j] = cvt_bf16(hv);
            }
            __hip_atomic_store((unsigned long long*)(hout + (size_t)m * 1024 + n),
                               __builtin_bit_cast(unsigned long long, hh),
                               __ATOMIC_RELAXED, __HIP_MEMORY_SCOPE_AGENT);
        }
        asm volatile("s_waitcnt vmcnt(0)" ::: "memory");   // h stores acked
        __syncthreads();

        if (s < 255 && tid == 0)
            __hip_atomic_store(&gflags[ni], (unsigned)(s + 1),
                               __ATOMIC_RELAXED, __HIP_MEMORY_SCOPE_AGENT);

        // out store AFTER flag publish: HBM ack off the critical path
        int tout = fwd ? ((239 - s) & 255) : s;
        __builtin_nontemporal_store(ov, (f32x4*)(outp + (size_t)tout * 2048));
    }
}

// ---------- launch ----------
extern "C" void kernel_launch(void* const* d_in, const int* in_sizes, int n_in,
                              void* d_out, int out_size, void* d_ws, size_t ws_size,
                              hipStream_t stream) {
    const float* x      = (const float*)d_in[0];
    const float* hidden = (const float*)d_in[1];
    const float* Wi     = (const float*)d_in[2];
    const float* bi     = (const float*)d_in[3];
    const float* Wh     = (const float*)d_in[4];
    const float* bh     = (const float*)d_in[5];
    float* out = (float*)d_out;

    char* ws = (char*)d_ws;
    float*          pre = (float*)ws;                               // 128 MB
    unsigned short* Wib = (unsigned short*)(ws + 134217728);        // 2 MB
    unsigned short* Whb = (unsigned short*)(ws + 136314880);        // 2 MB
    unsigned short* ha  = (unsigned short*)(ws + 138412032);        // 512 KB
    unsigned short* hb  = (unsigned short*)(ws + 138936320);        // 512 KB
    unsigned*     flags = (unsigned*)(ws + 139460608);              // 1 KB

    convert_w<<<dim3(512, 2), 256, 0, stream>>>(Wi, Wh, Wib, Whb);
    init_h<<<256, 256, 0, stream>>>(hidden, ha, flags);
    pre_gemm<<<dim3(8, 256), 256, 0, stream>>>(x, Wib, bi, pre);
    rnn_scan<<<256, 256, 0, stream>>>(Whb, pre, bh, ha, hb, out, flags);
}